// Round 7
// baseline (451.740 us; speedup 1.0000x reference)
//
#include <hip/hip_runtime.h>
#include <hip/hip_bf16.h>
#include <cstdint>

// ---------------- problem constants ----------------
#define NN      8192      // nodes
#define OF      64        // out features
#define KC      16        // K-chunks (KSPLIT)
#define CW      512       // K width per chunk
#define SLROWS  65        // B rows staged: 64 h-cols + 1 e-col (65..79 are zero)
#define SLSTR   520       // LDS row stride in shorts (1040B: conflict-free class)
#define PSTR    65        // slab row stride (floats): 64 cols + S

// ---------------- ws layout (bytes) ----------------
#define OFF_HW  0                           // HW 80x8192 u16          = 1310720
#define OFF_P   1310720                     // P16 16x8192x65 f32      = 34078720

typedef __attribute__((ext_vector_type(8))) short  s16x8;
typedef __attribute__((ext_vector_type(4))) float  f32x4;

__device__ __forceinline__ unsigned short f2bf(float f) {
  unsigned int u = __float_as_uint(f);
  unsigned int r = (u + 0x7FFFu + ((u >> 16) & 1u)) >> 16;   // RNE
  return (unsigned short)r;
}

// ---------------- k1: h = X @ W (LDS-tiled fp32) -> fused e/HW write -------
// bf16 B is safe: outputs are softmax-weighted means (N_eff ~ tens), RNE
// errors average down; measured absmax 7.8e-3 << 4e-2.
__global__ __launch_bounds__(256) void k1_hw(const float* __restrict__ X,
                                             const float* __restrict__ W,
                                             const float* __restrict__ att,
                                             unsigned short* __restrict__ HW) {
  __shared__ float xs[16 * 516];     // odd 16B-segment stride
  __shared__ float ws[64 * 68];
  int t = threadIdx.x;
  int rb = blockIdx.x * 16;

  {
    const float4* src = (const float4*)(X + (size_t)rb * 512);
#pragma unroll
    for (int s = 0; s < 8; ++s) {
      int lid = s * 256 + t;
      int row = lid >> 7, kseg = lid & 127;
      *(float4*)&xs[row * 516 + kseg * 4] = src[row * 128 + kseg];
    }
  }

  int row = t >> 4, tx = t & 15;     // thread: 1 row x 4 cols
  float4 acc = {0.f, 0.f, 0.f, 0.f};
  for (int kc = 0; kc < 8; ++kc) {
    __syncthreads();
#pragma unroll
    for (int s = 0; s < 4; ++s) {
      int lid = s * 256 + t;
      int k = lid >> 4, cs = lid & 15;
      *(float4*)&ws[k * 68 + cs * 4] =
          *(const float4*)(W + (size_t)(kc * 64 + k) * 64 + cs * 4);
    }
    __syncthreads();
#pragma unroll 16
    for (int k = 0; k < 64; ++k) {
      float x = xs[row * 516 + kc * 64 + k];
      float4 w4 = *(const float4*)&ws[k * 68 + tx * 4];
      acc.x += x * w4.x; acc.y += x * w4.y;
      acc.z += x * w4.z; acc.w += x * w4.w;
    }
  }

  float v = acc.x * att[64 + tx * 4]     + acc.y * att[64 + tx * 4 + 1] +
            acc.z * att[64 + tx * 4 + 2] + acc.w * att[64 + tx * 4 + 3];
#pragma unroll
  for (int m = 8; m > 0; m >>= 1) v += __shfl_xor(v, m, 64);
  float e = expf(v);                 // |r| <~ 21, no overflow

  int j = rb + row;
  unsigned short* hw = HW + j;
  float hv[4] = {acc.x, acc.y, acc.z, acc.w};
#pragma unroll
  for (int c = 0; c < 4; ++c)
    hw[(size_t)(tx * 4 + c) * NN] = f2bf(e * hv[c]);
  if (tx == 0) hw[(size_t)64 * NN] = f2bf(e);   // rows 65..79 never read
}

// ---------------- cvt: 8 int32 {0,1} -> 8 bf16 {0,1} (packed, 8 VALU) -----
__device__ __forceinline__ s16x8 cvt8(int4 a, int4 b) {
  union { unsigned u[4]; s16x8 v; } rr;
  rr.u[0] = (unsigned)(a.x | (a.y << 16)) * 0x3F80u;
  rr.u[1] = (unsigned)(a.z | (a.w << 16)) * 0x3F80u;
  rr.u[2] = (unsigned)(b.x | (b.y << 16)) * 0x3F80u;
  rr.u[3] = (unsigned)(b.z | (b.w << 16)) * 0x3F80u;
  return rr.v;
}

// ---------------- k3: B-resident-in-LDS, barrier-free A-streaming K-loop ---
// Block = (kc, mg): K-chunk kc (512 wide), rows mg*256..+255. B-slice staged
// to LDS ONCE; then each wave sweeps 4 m-tiles x 8 k-steps with NO barriers,
// A prefetched 1 step ahead (loads stay in flight; no vmcnt(0) drains).
__global__ __launch_bounds__(256, 2) void k3_gat(const int* __restrict__ A,
                                                 const unsigned short* __restrict__ HW,
                                                 float* __restrict__ P) {
  __shared__ unsigned short bt[SLROWS * SLSTR];    // 67600 B -> 2 blocks/CU

  int t = threadIdx.x;
  int kc = blockIdx.x & 15;                        // K-chunk (XCD-affine)
  int mg = blockIdx.x >> 4;                        // 0..31 row-groups
  int lane = t & 63, w = t >> 6;
  int l15 = lane & 15, q = lane >> 4;
  int k0 = kc * CW;

  // stage B rows 0..64 (4160 16B-segments; 16 full rounds + 64-thread tail)
#pragma unroll
  for (int i = 0; i < 16; ++i) {
    int lid = i * 256 + t;
    int row = lid >> 6, sg = lid & 63;
    *(uint4*)&bt[row * SLSTR + sg * 8] =
        *(const uint4*)(HW + (size_t)row * NN + k0 + sg * 8);
  }
  if (t < 64)
    *(uint4*)&bt[64 * SLSTR + t * 8] =
        *(const uint4*)(HW + (size_t)64 * NN + k0 + t * 8);
  __syncthreads();                                 // the ONLY barrier

  float* Pp = P + (size_t)kc * NN * PSTR;
  const s16x8 zero8 = {0, 0, 0, 0, 0, 0, 0, 0};

  for (int mt = 0; mt < 4; ++mt) {
    int rowM = mg * 256 + w * 64 + mt * 16;
    const int* ar = A + (size_t)(rowM + l15) * NN + k0 + q * 8;

    f32x4 acc[5];
#pragma unroll
    for (int tt = 0; tt < 5; ++tt) acc[tt] = 0.f;

    int4 c0 = *(const int4*)(ar);
    int4 c1 = *(const int4*)(ar + 4);
    int4 c2 = *(const int4*)(ar + 32);
    int4 c3 = *(const int4*)(ar + 36);
    ar += 64;

#pragma unroll
    for (int step = 0; step < 8; ++step) {
      int4 n0, n1, n2, n3;
      if (step != 7) {
        n0 = *(const int4*)(ar);
        n1 = *(const int4*)(ar + 4);
        n2 = *(const int4*)(ar + 32);
        n3 = *(const int4*)(ar + 36);
        ar += 64;
      }

      s16x8 af0 = cvt8(c0, c1);
      s16x8 af1 = cvt8(c2, c3);

#pragma unroll
      for (int ks = 0; ks < 2; ++ks) {
        s16x8 af = ks ? af1 : af0;
        int kb = step * 64 + ks * 32 + q * 8;
#pragma unroll
        for (int tt = 0; tt < 4; ++tt) {
          s16x8 b = *(const s16x8*)&bt[(tt * 16 + l15) * SLSTR + kb];
          acc[tt] = __builtin_amdgcn_mfma_f32_16x16x32_bf16(af, b, acc[tt], 0, 0, 0);
        }
        // tt=4: only col 64 (e-row) is nonzero; broadcast row-64 read + select
        s16x8 b4 = *(const s16x8*)&bt[64 * SLSTR + kb];
        b4 = (l15 == 0) ? b4 : zero8;
        acc[4] = __builtin_amdgcn_mfma_f32_16x16x32_bf16(af, b4, acc[4], 0, 0, 0);
      }

      c0 = n0; c1 = n1; c2 = n2; c3 = n3;
    }

    // store m-tile partials: C/D layout col=l15, row=q*4+rg
    int rb = rowM + q * 4;
#pragma unroll
    for (int tt = 0; tt < 4; ++tt)
#pragma unroll
      for (int rg = 0; rg < 4; ++rg)
        Pp[(size_t)(rb + rg) * PSTR + tt * 16 + l15] = acc[tt][rg];
    if (l15 == 0)
#pragma unroll
      for (int rg = 0; rg < 4; ++rg)
        Pp[(size_t)(rb + rg) * PSTR + 64] = acc[4][rg];
  }
}

// ---------------- k4: reduce 16 slabs + normalize + ELU ----------------
__global__ __launch_bounds__(256) void k4_fin(const float* __restrict__ P,
                                              float* __restrict__ out) {
  int g = blockIdx.x * 256 + threadIdx.x;          // 524288
  int i = g >> 6, c = g & 63;
  float num = 0.f, S = 0.f;
#pragma unroll
  for (int kc = 0; kc < KC; ++kc) {
    const float* p = P + (size_t)kc * NN * PSTR + (size_t)i * PSTR;
    num += p[c];
    S   += p[64];
  }
  float x = num / S;
  out[g] = x > 0.f ? x : expm1f(x);
}

extern "C" void kernel_launch(void* const* d_in, const int* in_sizes, int n_in,
                              void* d_out, int out_size, void* d_ws, size_t ws_size,
                              hipStream_t stream) {
  const float* X  = (const float*)d_in[0];   // 8192x512
  const int*   A  = (const int*)d_in[1];     // 8192x8192
  const float* W  = (const float*)d_in[2];   // 512x64
  const float* av = (const float*)d_in[3];   // 128x1
  float* out = (float*)d_out;

  char* ws = (char*)d_ws;
  unsigned short* HW = (unsigned short*)(ws + OFF_HW);
  float*          P  = (float*)(ws + OFF_P);

  k1_hw<<<NN / 16, 256, 0, stream>>>(X, W, av, HW);
  k3_gat<<<512, 256, 0, stream>>>(A, HW, P);
  k4_fin<<<(size_t)NN * OF / 256, 256, 0, stream>>>(P, out);
}

// Round 8
// 396.290 us; speedup vs baseline: 1.1399x; 1.1399x over previous
//
#include <hip/hip_runtime.h>
#include <hip/hip_bf16.h>
#include <cstdint>

// ---------------- problem constants ----------------
#define NN      8192      // nodes
#define OF      64        // out features
#define KC      16        // K-chunks
#define CW      512       // K width per chunk (elements)
#define ASTR    72        // A LDS tile stride (shorts) -> 2-way banks only
#define PSTR    65        // P slab row stride (floats): 64 cols + S

// ---------------- ws layout (bytes) ----------------
#define OFF_HW  0                           // HW 80x8192 u16          = 1310720
#define OFF_P   1310720                     // P16 16x8192x65 f32      = 34078720

typedef __attribute__((ext_vector_type(8))) short  s16x8;
typedef __attribute__((ext_vector_type(4))) float  f32x4;

__device__ __forceinline__ unsigned short f2bf(float f) {
  unsigned int u = __float_as_uint(f);
  unsigned int r = (u + 0x7FFFu + ((u >> 16) & 1u)) >> 16;   // RNE
  return (unsigned short)r;
}

// lgkm-only barrier: does NOT drain vmcnt -> A prefetch stays in flight.
// SIMM16: vmcnt=63 (no wait) bits[3:0]+[15:14], expcnt=7, lgkmcnt=0.
__device__ __forceinline__ void lds_barrier() {
  __builtin_amdgcn_s_waitcnt(0xC07F);
  __builtin_amdgcn_s_barrier();
}

// ---------------- k1: h = X @ W (LDS-tiled fp32) -> fused e/HW write -------
__global__ __launch_bounds__(256) void k1_hw(const float* __restrict__ X,
                                             const float* __restrict__ W,
                                             const float* __restrict__ att,
                                             unsigned short* __restrict__ HW) {
  __shared__ float xs[16 * 516];
  __shared__ float ws[64 * 68];
  int t = threadIdx.x;
  int rb = blockIdx.x * 16;

  {
    const float4* src = (const float4*)(X + (size_t)rb * 512);
#pragma unroll
    for (int s = 0; s < 8; ++s) {
      int lid = s * 256 + t;
      int row = lid >> 7, kseg = lid & 127;
      *(float4*)&xs[row * 516 + kseg * 4] = src[row * 128 + kseg];
    }
  }

  int row = t >> 4, tx = t & 15;
  float4 acc = {0.f, 0.f, 0.f, 0.f};
  for (int kc = 0; kc < 8; ++kc) {
    __syncthreads();
#pragma unroll
    for (int s = 0; s < 4; ++s) {
      int lid = s * 256 + t;
      int k = lid >> 4, cs = lid & 15;
      *(float4*)&ws[k * 68 + cs * 4] =
          *(const float4*)(W + (size_t)(kc * 64 + k) * 64 + cs * 4);
    }
    __syncthreads();
#pragma unroll 16
    for (int k = 0; k < 64; ++k) {
      float x = xs[row * 516 + kc * 64 + k];
      float4 w4 = *(const float4*)&ws[k * 68 + tx * 4];
      acc.x += x * w4.x; acc.y += x * w4.y;
      acc.z += x * w4.z; acc.w += x * w4.w;
    }
  }

  float v = acc.x * att[64 + tx * 4]     + acc.y * att[64 + tx * 4 + 1] +
            acc.z * att[64 + tx * 4 + 2] + acc.w * att[64 + tx * 4 + 3];
#pragma unroll
  for (int m = 8; m > 0; m >>= 1) v += __shfl_xor(v, m, 64);
  float e = expf(v);                 // |r| <~ 21, no overflow

  int j = rb + row;
  unsigned short* hw = HW + j;
  float hv[4] = {acc.x, acc.y, acc.z, acc.w};
#pragma unroll
  for (int c = 0; c < 4; ++c)
    hw[(size_t)(tx * 4 + c) * NN] = f2bf(e * hv[c]);
  if (tx == 0) hw[(size_t)64 * NN] = f2bf(e);   // rows 65..79 never read
}

// ---------------- k3: contiguous A-stream through LDS, swizzled resident B -
// Block = (kc, mg): rows mg*64, K span [kc*512,+512). B staged once (XOR-
// swizzled, conflict-free). Per step: A loaded with FULLY CONTIGUOUS instrs
// (4 rows x 256B/row per dwordx4), cvt to bf16, through a 9.2KB LDS tile.
// lgkm-only barriers never drain vmcnt; depth-2 VGPR prefetch.
__global__ __launch_bounds__(256, 2) void k3_gat(const int* __restrict__ A,
                                                 const unsigned short* __restrict__ HW,
                                                 float* __restrict__ P) {
  __shared__ unsigned short bt[65 * 512];   // 66560 B, swizzled B
  __shared__ unsigned short at[64 * ASTR];  //  9216 B, A tile (bf16)

  int t = threadIdx.x;
  int kc = blockIdx.x & 15;                 // XCD-affine B slice
  int mg = blockIdx.x >> 4;                 // 0..127
  int lane = t & 63, w = t >> 6;
  int l15 = lane & 15, q = lane >> 4;
  int k0 = kc * CW;
  int rowM = mg * 64;

  // A prefetch pointers: instr i covers rows w*16+i*4+q, 16 lanes x 16B contig
  const int* ap[4];
#pragma unroll
  for (int i = 0; i < 4; ++i)
    ap[i] = A + (size_t)(rowM + w * 16 + i * 4 + q) * NN + k0 + l15 * 4;

  int4 av[3][4];
#pragma unroll
  for (int i = 0; i < 4; ++i) av[0][i] = *(const int4*)(ap[i]);        // s=0
#pragma unroll
  for (int i = 0; i < 4; ++i) av[1][i] = *(const int4*)(ap[i] + 64);   // s=1

  // stage B swizzled: chunk ch of row goes to position ch ^ (row & 7)
#pragma unroll
  for (int rds = 0; rds < 16; ++rds) {
    int lid = rds * 256 + t;
    int row = lid >> 6, ch = lid & 63;
    uint4 v = *(const uint4*)(HW + (size_t)row * NN + k0 + ch * 8);
    *(uint4*)&bt[row * 512 + ((ch ^ (row & 7)) * 8)] = v;
  }
  if (t < 64) {                             // row 64 (e-row), swz = 0
    uint4 v = *(const uint4*)(HW + (size_t)64 * NN + k0 + t * 8);
    *(uint4*)&bt[64 * 512 + t * 8] = v;
  }

  // ds_read byte-address bases
  int swz = l15 & 7;
  int bb[4][2];
#pragma unroll
  for (int tt = 0; tt < 4; ++tt)
#pragma unroll
    for (int ks = 0; ks < 2; ++ks)
      bb[tt][ks] = ((tt * 16 + l15) * 512 + (((ks * 4 + q) ^ swz) * 8)) * 2;
  int eb0 = (64 * 512 + q * 8) * 2;
  int eb1 = (64 * 512 + (4 + q) * 8) * 2;
  int ab  = ((w * 16 + l15) * ASTR + q * 8) * 2;

  f32x4 acc[5];
#pragma unroll
  for (int tt = 0; tt < 5; ++tt) acc[tt] = 0.f;
  const s16x8 zero8 = {0, 0, 0, 0, 0, 0, 0, 0};

#pragma unroll
  for (int s = 0; s < 8; ++s) {
    lds_barrier();                          // prior step's tile reads done
    // write A(s) -> tile (cvt int{0,1} -> bf16 packed, 8B/lane/instr-group)
#pragma unroll
    for (int i = 0; i < 4; ++i) {
      int4 vv = av[s % 3][i];
      uint2 p;
      p.x = (unsigned)(vv.x | (vv.y << 16)) * 0x3F80u;
      p.y = (unsigned)(vv.z | (vv.w << 16)) * 0x3F80u;
      *(uint2*)((char*)at + (((w * 16 + i * 4 + q) * ASTR + l15 * 4) * 2)) = p;
    }
    if (s < 6) {
#pragma unroll
      for (int i = 0; i < 4; ++i)
        av[(s + 2) % 3][i] = *(const int4*)(ap[i] + (s + 2) * 64);
    }
    lds_barrier();                          // tile ready

    s16x8 af0 = *(const s16x8*)((char*)at + ab);
    s16x8 af1 = *(const s16x8*)((char*)at + ab + 64);
    int so = s * 128;                       // step byte offset within B row
#pragma unroll
    for (int ks = 0; ks < 2; ++ks) {
      s16x8 af = ks ? af1 : af0;
#pragma unroll
      for (int tt = 0; tt < 4; ++tt) {
        s16x8 b = *(const s16x8*)((char*)bt + bb[tt][ks] + so);
        acc[tt] = __builtin_amdgcn_mfma_f32_16x16x32_bf16(af, b, acc[tt], 0, 0, 0);
      }
      s16x8 b4 = *(const s16x8*)((char*)bt + (ks ? eb1 : eb0) + so);
      b4 = (l15 == 0) ? b4 : zero8;
      acc[4] = __builtin_amdgcn_mfma_f32_16x16x32_bf16(af, b4, acc[4], 0, 0, 0);
    }
  }

  // epilogue: C/D layout col=l15, row=q*4+rg
  float* Pp = P + (size_t)kc * NN * PSTR;
  int rb = rowM + w * 16 + q * 4;
#pragma unroll
  for (int tt = 0; tt < 4; ++tt)
#pragma unroll
    for (int rg = 0; rg < 4; ++rg)
      Pp[(size_t)(rb + rg) * PSTR + tt * 16 + l15] = acc[tt][rg];
  if (l15 == 0)
#pragma unroll
    for (int rg = 0; rg < 4; ++rg)
      Pp[(size_t)(rb + rg) * PSTR + 64] = acc[4][rg];
}

// ---------------- k4: reduce 16 slabs + normalize + ELU ----------------
__global__ __launch_bounds__(256) void k4_fin(const float* __restrict__ P,
                                              float* __restrict__ out) {
  int g = blockIdx.x * 256 + threadIdx.x;          // 524288
  int i = g >> 6, c = g & 63;
  float num = 0.f, S = 0.f;
#pragma unroll
  for (int kc = 0; kc < KC; ++kc) {
    const float* p = P + (size_t)kc * NN * PSTR + (size_t)i * PSTR;
    num += p[c];
    S   += p[64];
  }
  float x = num / S;
  out[g] = x > 0.f ? x : expm1f(x);
}

extern "C" void kernel_launch(void* const* d_in, const int* in_sizes, int n_in,
                              void* d_out, int out_size, void* d_ws, size_t ws_size,
                              hipStream_t stream) {
  const float* X  = (const float*)d_in[0];   // 8192x512
  const int*   A  = (const int*)d_in[1];     // 8192x8192
  const float* W  = (const float*)d_in[2];   // 512x64
  const float* av = (const float*)d_in[3];   // 128x1
  float* out = (float*)d_out;

  char* ws = (char*)d_ws;
  unsigned short* HW = (unsigned short*)(ws + OFF_HW);
  float*          P  = (float*)(ws + OFF_P);

  k1_hw<<<NN / 16, 256, 0, stream>>>(X, W, av, HW);
  k3_gat<<<128 * KC, 256, 0, stream>>>(A, HW, P);
  k4_fin<<<(size_t)NN * OF / 256, 256, 0, stream>>>(P, out);
}